// Round 2
// baseline (684.273 us; speedup 1.0000x reference)
//
#include <hip/hip_runtime.h>
#include <hip/hip_bf16.h>
#include <stdint.h>

// MoE LoRA: N=16384, D_IN=4096, D_OUT=4096, RANK=64, TOPK=8.
// v3: single fused kernel, one row per WAVE, no LDS, no barriers.
//   - phase1: gathered dots vs down_w, 2-deep software pipeline (9 float4
//     loads in flight ahead of compute) under __launch_bounds__(256,4)
//     (VGPR cap 128) -- fixes v2's VGPR=60 latency serialization.
//   - butterfly shfl_xor reduce leaves sums in ALL lanes -> phase2 runs
//     immediately in-wave against transposed up_t (fp32, L2-resident).
// Dtype self-detection kept (probe sets flags; fp32/bf16 paths).
#define NROWS 16384
#define D_IN  4096
#define D_OUT 4096
#define RANK  64
#define TOPK  8

typedef __hip_bfloat16 bf16;

__device__ int g_is_fp32;   // 1 if tensors are fp32, 0 if bf16
__device__ int g_idx64;     // 1 if indices are int64 on device, 0 if int32
__device__ float g_up_t[RANK * D_OUT];   // transposed up_w, fp32 internal (1 MB)

__device__ __forceinline__ void unpack8(uint4 raw, float f[8]) {
    const unsigned u0 = raw.x, u1 = raw.y, u2 = raw.z, u3 = raw.w;
    f[0] = __uint_as_float(u0 << 16);
    f[1] = __uint_as_float(u0 & 0xffff0000u);
    f[2] = __uint_as_float(u1 << 16);
    f[3] = __uint_as_float(u1 & 0xffff0000u);
    f[4] = __uint_as_float(u2 << 16);
    f[5] = __uint_as_float(u2 & 0xffff0000u);
    f[6] = __uint_as_float(u3 << 16);
    f[7] = __uint_as_float(u3 & 0xffff0000u);
}

// ---- probe: decide dtypes from raw bits (verified r0/r1) ----
__global__ void probe_dtypes(const unsigned short* __restrict__ hid_u16,
                             const int* __restrict__ idx_i32) {
    if (threadIdx.x != 0 || blockIdx.x != 0) return;
    int plausible = 0;
    for (int i = 0; i < 64; i += 2) {
        int e = (hid_u16[i] >> 7) & 0xff;
        if (e >= 0x70 && e <= 0x8a) plausible++;
    }
    g_is_fp32 = (plausible < 16) ? 1 : 0;
    int oddnz = 0;
    for (int i = 1; i < 64; i += 2)
        if (idx_i32[i] != 0) oddnz++;
    g_idx64 = (oddnz == 0) ? 1 : 0;
}

// ---- transpose up_w [D_OUT][RANK] -> g_up_t [RANK][D_OUT] (fp32, verified) ----
__global__ __launch_bounds__(256) void transpose_up(const void* __restrict__ up_w) {
    const int m = blockIdx.x * 256 + threadIdx.x;
    const int r = m >> 12;            // / D_OUT
    const int o = m & (D_OUT - 1);
    float v;
    if (g_is_fp32) v = ((const float*)up_w)[o * RANK + r];
    else           v = __bfloat162float(((const bf16*)up_w)[o * RANK + r]);
    g_up_t[m] = v;
}

__global__ __launch_bounds__(256, 4) void moe_fused(
    const void* __restrict__ hidden,     // [N, D_IN]
    const void* __restrict__ down_w,     // [RANK, D_IN]
    const void* __restrict__ topk_vals,  // [N, TOPK]
    const void* __restrict__ topk_idx,   // [N, TOPK]
    void* __restrict__ out)              // [N, D_OUT]
{
    const int lane = threadIdx.x & 63;
    const int n = blockIdx.x * 4 + (threadIdx.x >> 6);
    const bool fp32 = (g_is_fp32 != 0);
    const bool idx64 = (g_idx64 != 0);

    int woff[TOPK];   // element offsets of gathered rows (D_IN == D_OUT)
#pragma unroll
    for (int k = 0; k < TOPK; ++k) {
        const int m = n * TOPK + k;
        const int v = idx64 ? ((const int*)topk_idx)[2 * m]
                            : ((const int*)topk_idx)[m];
        woff[k] = (v & (RANK - 1)) * D_IN;
    }

    // ---- phase 1: acc[k] = dot(hidden[n], down_w[idx_k]) ----
    float acc[TOPK];
#pragma unroll
    for (int k = 0; k < TOPK; ++k) acc[k] = 0.0f;

    if (fp32) {
        const float* hrow = (const float*)hidden + (size_t)n * D_IN;
        const float* dw   = (const float*)down_w;
        // 2-deep software pipeline: next iter's 9 loads in flight over compute
        float4 hc, wc[TOPK];
        {
            const int off = lane * 4;
            hc = *reinterpret_cast<const float4*>(hrow + off);
#pragma unroll
            for (int k = 0; k < TOPK; ++k)
                wc[k] = *reinterpret_cast<const float4*>(dw + woff[k] + off);
        }
#pragma unroll
        for (int i = 0; i < 16; ++i) {
            float4 hn, wn[TOPK];
            if (i < 15) {
                const int noff = (i + 1) * 256 + lane * 4;
                hn = *reinterpret_cast<const float4*>(hrow + noff);
#pragma unroll
                for (int k = 0; k < TOPK; ++k)
                    wn[k] = *reinterpret_cast<const float4*>(dw + woff[k] + noff);
            }
#pragma unroll
            for (int k = 0; k < TOPK; ++k) {
                acc[k] = fmaf(hc.x, wc[k].x, acc[k]);
                acc[k] = fmaf(hc.y, wc[k].y, acc[k]);
                acc[k] = fmaf(hc.z, wc[k].z, acc[k]);
                acc[k] = fmaf(hc.w, wc[k].w, acc[k]);
            }
            if (i < 15) {
                hc = hn;
#pragma unroll
                for (int k = 0; k < TOPK; ++k) wc[k] = wn[k];
            }
        }
    } else {
        const bf16* hrow = (const bf16*)hidden + (size_t)n * D_IN;
        const bf16* dw   = (const bf16*)down_w;
#pragma unroll
        for (int i = 0; i < 8; ++i) {
            const int off = i * 512 + lane * 8;
            float h[8];
            unpack8(*reinterpret_cast<const uint4*>(hrow + off), h);
#pragma unroll
            for (int k = 0; k < TOPK; ++k) {
                float w[8];
                unpack8(*reinterpret_cast<const uint4*>(dw + woff[k] + off), w);
#pragma unroll
                for (int j = 0; j < 8; ++j) acc[k] = fmaf(h[j], w[j], acc[k]);
            }
        }
    }

    // ---- butterfly reduce: every lane ends with the full sums ----
#pragma unroll
    for (int k = 0; k < TOPK; ++k) {
#pragma unroll
        for (int d = 32; d > 0; d >>= 1)
            acc[k] += __shfl_xor(acc[k], d, 64);
    }

    float s[TOPK];
#pragma unroll
    for (int k = 0; k < TOPK; ++k) {
        const int m = n * TOPK + k;
        const float scale = fp32 ? ((const float*)topk_vals)[m]
                                 : __bfloat162float(((const bf16*)topk_vals)[m]);
        s[k] = acc[k] * scale;
    }

    // ---- phase 2: out[n, o] = sum_k s_k * up_t[idx_k, o] ----
    if (fp32) {
        float* orow = (float*)out + (size_t)n * D_OUT;
        float4 uc[TOPK];
        {
            const int off = lane * 4;
#pragma unroll
            for (int k = 0; k < TOPK; ++k)
                uc[k] = *reinterpret_cast<const float4*>(g_up_t + woff[k] + off);
        }
#pragma unroll
        for (int i = 0; i < 16; ++i) {
            float4 un[TOPK];
            if (i < 15) {
                const int noff = (i + 1) * 256 + lane * 4;
#pragma unroll
                for (int k = 0; k < TOPK; ++k)
                    un[k] = *reinterpret_cast<const float4*>(g_up_t + woff[k] + noff);
            }
            float4 a = make_float4(0.f, 0.f, 0.f, 0.f);
#pragma unroll
            for (int k = 0; k < TOPK; ++k) {
                a.x = fmaf(s[k], uc[k].x, a.x);
                a.y = fmaf(s[k], uc[k].y, a.y);
                a.z = fmaf(s[k], uc[k].z, a.z);
                a.w = fmaf(s[k], uc[k].w, a.w);
            }
            *reinterpret_cast<float4*>(orow + i * 256 + lane * 4) = a;
            if (i < 15) {
#pragma unroll
                for (int k = 0; k < TOPK; ++k) uc[k] = un[k];
            }
        }
    } else {
        bf16* orow = (bf16*)out + (size_t)n * D_OUT;
#pragma unroll
        for (int i = 0; i < 8; ++i) {
            const int o = i * 512 + lane * 8;
            float accO[8];
#pragma unroll
            for (int j = 0; j < 8; ++j) accO[j] = 0.0f;
#pragma unroll
            for (int k = 0; k < TOPK; ++k) {
                const float4 u0 = *reinterpret_cast<const float4*>(g_up_t + woff[k] + o);
                const float4 u1 = *reinterpret_cast<const float4*>(g_up_t + woff[k] + o + 4);
                const float sk = s[k];
                accO[0] = fmaf(sk, u0.x, accO[0]);
                accO[1] = fmaf(sk, u0.y, accO[1]);
                accO[2] = fmaf(sk, u0.z, accO[2]);
                accO[3] = fmaf(sk, u0.w, accO[3]);
                accO[4] = fmaf(sk, u1.x, accO[4]);
                accO[5] = fmaf(sk, u1.y, accO[5]);
                accO[6] = fmaf(sk, u1.z, accO[6]);
                accO[7] = fmaf(sk, u1.w, accO[7]);
            }
            union { uint4 v; bf16 h[8]; } ou;
#pragma unroll
            for (int j = 0; j < 8; ++j) ou.h[j] = __float2bfloat16(accO[j]);
            *reinterpret_cast<uint4*>(orow + o) = ou.v;
        }
    }
}

extern "C" void kernel_launch(void* const* d_in, const int* in_sizes, int n_in,
                              void* d_out, int out_size, void* d_ws, size_t ws_size,
                              hipStream_t stream) {
    const void* hidden = d_in[0];   // [N, D_IN]
    const void* down_w = d_in[1];   // [RANK, D_IN]
    const void* up_w   = d_in[2];   // [D_OUT, RANK]
    const void* vals   = d_in[3];   // [N, TOPK]
    const void* idx    = d_in[4];   // [N, TOPK]

    probe_dtypes<<<1, 64, 0, stream>>>((const unsigned short*)hidden, (const int*)idx);
    transpose_up<<<(RANK * D_OUT) / 256, 256, 0, stream>>>(up_w);
    moe_fused<<<NROWS / 4, 256, 0, stream>>>(hidden, down_w, vals, idx, d_out);
}